// Round 5
// baseline (152.584 us; speedup 1.0000x reference)
//
#include <hip/hip_runtime.h>

#define B_BATCH 16
#define XLEN    320000
#define NFFT    2048
#define HOP     512
#define PADW    1024
#define NFREQ   1025
#define T_OUT   626
#define M_ROWS  2050
#define NCOLS   (B_BATCH * T_OUT)          // 10016
#define MT2     17                          // ceil(2050/128)
#define NT3     79                          // ceil(10016/128)
#define NBLK    (MT2 * NT3)                 // 1343 = 8*167 + 7
#define KT2     32                          // 2048/64

#define XPAD_LEN    322048                  // XLEN + 2*PADW
#define XPAD_STRIDE 330240
#define APACK_BYTES ((size_t)MT2 * KT2 * 2 * 8192)             // 8,912,896
#define XPAD_BYTES  ((size_t)(B_BATCH + 1) * XPAD_STRIDE * 2)  // 11,228,160 (slot 16 = zeros)
#define WS_NEEDED   (APACK_BYTES + XPAD_BYTES)

typedef __bf16 bf16x8 __attribute__((ext_vector_type(8)));
typedef __bf16 bf16x4 __attribute__((ext_vector_type(4)));
typedef float  f32x4  __attribute__((ext_vector_type(4)));

__device__ __forceinline__ void gload_lds16(const void* g, void* l) {
    __builtin_amdgcn_global_load_lds(
        (const __attribute__((address_space(1))) unsigned int*)g,
        (__attribute__((address_space(3))) unsigned int*)l,
        16, 0, 0);
}

// ---------------- prep A: weights fp32 -> bf16, packed in exact LDS-slot layout ----
// Half-slot ph = kt*2+ks (64 per mt), 8 KB each: byte row*64 + scell*16 holds
// W[mt*128+row][ph*32 + (((scell ^ (row>>1)) & 3)<<3) + e], e in [0,8).
__global__ __launch_bounds__(256) void prep_w(
    const float* __restrict__ wre, const float* __restrict__ wim,
    __bf16* __restrict__ apack)
{
    const int gid   = blockIdx.x * 256 + threadIdx.x;  // 557056 total
    const int scell = gid & 3;
    const int row   = (gid >> 2) & 127;
    const int ph    = (gid >> 9) & 63;
    const int mt    = gid >> 15;

    const int grow = mt * 128 + row;
    const int k    = ph * 32 + (((scell ^ (row >> 1)) & 3) << 3);

    bf16x8 v = bf16x8{};
    if (grow < M_ROWS) {
        const float* src = (grow < NFREQ)
            ? (wre + (size_t)grow * NFFT + k)
            : (wim + (size_t)(grow - NFREQ) * NFFT + k);
        const float4 a = *reinterpret_cast<const float4*>(src);
        const float4 b = *reinterpret_cast<const float4*>(src + 4);
        v[0] = (__bf16)a.x; v[1] = (__bf16)a.y; v[2] = (__bf16)a.z; v[3] = (__bf16)a.w;
        v[4] = (__bf16)b.x; v[5] = (__bf16)b.y; v[6] = (__bf16)b.z; v[7] = (__bf16)b.w;
    }
    *reinterpret_cast<bf16x8*>(apack + (size_t)gid * 8) = v;
}

// ---------------- prep B: reflect-padded signal fp32 -> bf16 (slot 16 = zeros) ----
__global__ __launch_bounds__(256) void prep_x(
    const float* __restrict__ x, __bf16* __restrict__ xpad)
{
    const int gid = blockIdx.x * 256 + threadIdx.x;
    if (gid >= (B_BATCH + 1) * (XPAD_STRIDE / 8)) return;
    const int b  = gid / (XPAD_STRIDE / 8);
    const int i0 = (gid - b * (XPAD_STRIDE / 8)) * 8;

    bf16x8 v = bf16x8{};
    if (b < B_BATCH) {
        const float* xb = x + (size_t)b * XLEN;
        const int pos0 = i0 - PADW;
        if (pos0 >= 0 && pos0 + 8 <= XLEN) {
            const float4 a = *reinterpret_cast<const float4*>(xb + pos0);
            const float4 c = *reinterpret_cast<const float4*>(xb + pos0 + 4);
            v[0] = (__bf16)a.x; v[1] = (__bf16)a.y; v[2] = (__bf16)a.z; v[3] = (__bf16)a.w;
            v[4] = (__bf16)c.x; v[5] = (__bf16)c.y; v[6] = (__bf16)c.z; v[7] = (__bf16)c.w;
        } else {
            #pragma unroll
            for (int e = 0; e < 8; ++e) {
                const int i = i0 + e;
                if (i >= XPAD_LEN) { v[e] = (__bf16)0.f; continue; }
                int p = i - PADW;
                p = (p < 0) ? -p : p;
                p = (p >= XLEN) ? (2 * XLEN - 2 - p) : p;
                v[e] = (__bf16)xb[p];
            }
        }
    }
    *reinterpret_cast<bf16x8*>(xpad + (size_t)b * XPAD_STRIDE + i0) = v;
}

// ---------------- main GEMM: reg-double-buffered fragments, 3-slot LDS pipeline ----
// 64 phases (32 K-elems each). Phase p: STG(p+2) -> vmcnt(4) (drains stage p+1)
// -> barrier -> ds_read phase-(p+1) frags into NXT regs -> 16 MFMA on CUR regs
// -> lgkmcnt(0). LDS = 3 slots x (8K A + 8K B) = 48 KB -> 3 blocks/CU.

#define MFMA16 __builtin_amdgcn_mfma_f32_16x16x32_bf16

#define VM4 asm volatile("s_waitcnt vmcnt(4)" ::: "memory");
#define VM0 asm volatile("s_waitcnt vmcnt(0)" ::: "memory");

#define STGM(PH_, SLOT_) {                                                        \
    const char* as_ = ablk + ((size_t)(PH_) << 13);                               \
    unsigned char* ad_ = lds + ((SLOT_) << 13) + (wid << 11);                     \
    gload_lds16(as_, ad_);                                                        \
    gload_lds16(as_ + 1024, ad_ + 1024);                                          \
    const int ko_ = (PH_) << 6;                                                   \
    unsigned char* bd_ = lds + 24576 + ((SLOT_) << 13) + (wid << 11);             \
    gload_lds16(gb0 + ko_, bd_);                                                  \
    gload_lds16(gb1 + ko_, bd_ + 1024);                                           \
}

#define MFMA_CLUSTER(A0,A1,A2,A3,B0,B1,B2,B3)                                     \
    acc[0][0] = MFMA16(A0, B0, acc[0][0], 0, 0, 0);                               \
    acc[0][1] = MFMA16(A0, B1, acc[0][1], 0, 0, 0);                               \
    acc[0][2] = MFMA16(A0, B2, acc[0][2], 0, 0, 0);                               \
    acc[0][3] = MFMA16(A0, B3, acc[0][3], 0, 0, 0);                               \
    acc[1][0] = MFMA16(A1, B0, acc[1][0], 0, 0, 0);                               \
    acc[1][1] = MFMA16(A1, B1, acc[1][1], 0, 0, 0);                               \
    acc[1][2] = MFMA16(A1, B2, acc[1][2], 0, 0, 0);                               \
    acc[1][3] = MFMA16(A1, B3, acc[1][3], 0, 0, 0);                               \
    acc[2][0] = MFMA16(A2, B0, acc[2][0], 0, 0, 0);                               \
    acc[2][1] = MFMA16(A2, B1, acc[2][1], 0, 0, 0);                               \
    acc[2][2] = MFMA16(A2, B2, acc[2][2], 0, 0, 0);                               \
    acc[2][3] = MFMA16(A2, B3, acc[2][3], 0, 0, 0);                               \
    acc[3][0] = MFMA16(A3, B0, acc[3][0], 0, 0, 0);                               \
    acc[3][1] = MFMA16(A3, B1, acc[3][1], 0, 0, 0);                               \
    acc[3][2] = MFMA16(A3, B2, acc[3][2], 0, 0, 0);                               \
    acc[3][3] = MFMA16(A3, B3, acc[3][3], 0, 0, 0);

#define PHASE(SLN_, STG_, VMW_, CA0,CA1,CA2,CA3,CB0,CB1,CB2,CB3,                  \
              NA0,NA1,NA2,NA3,NB0,NB1,NB2,NB3) {                                  \
    STG_                                                                          \
    VMW_                                                                          \
    __builtin_amdgcn_s_barrier();                                                 \
    __builtin_amdgcn_sched_barrier(0);                                            \
    {                                                                             \
        const unsigned ab_ = ((unsigned)(SLN_) << 13) + offA_base;                \
        const unsigned bb_ = ((unsigned)(SLN_) << 13) + offB_base;                \
        NA0 = *(const bf16x8*)(lds + ab_);                                        \
        NA1 = *(const bf16x8*)(lds + ab_ + 1024);                                 \
        NA2 = *(const bf16x8*)(lds + ab_ + 2048);                                 \
        NA3 = *(const bf16x8*)(lds + ab_ + 3072);                                 \
        NB0 = *(const bf16x8*)(lds + bb_);                                        \
        NB1 = *(const bf16x8*)(lds + bb_ + 1024);                                 \
        NB2 = *(const bf16x8*)(lds + bb_ + 2048);                                 \
        NB3 = *(const bf16x8*)(lds + bb_ + 3072);                                 \
    }                                                                             \
    __builtin_amdgcn_s_setprio(1);                                                \
    MFMA_CLUSTER(CA0,CA1,CA2,CA3,CB0,CB1,CB2,CB3)                                 \
    __builtin_amdgcn_s_setprio(0);                                                \
    asm volatile("s_waitcnt lgkmcnt(0)" ::: "memory");                            \
    __builtin_amdgcn_sched_barrier(0);                                            \
}

__global__ __launch_bounds__(256, 3) void stft_gemm5(
    const __bf16* __restrict__ apack,
    const __bf16* __restrict__ xpad,
    float* __restrict__ out)
{
    __shared__ __align__(16) unsigned char lds[49152];   // 48 KB -> 3 blocks/CU

    const int tid  = threadIdx.x;
    const int lane = tid & 63;
    const int wid  = tid >> 6;   // 0..3
    const int wm   = wid >> 1;   // 0..1
    const int wn   = wid & 1;    // 0..1
    const int fr   = lane & 15;
    const int kq   = lane >> 4;

    // bijective XCD-chunked swizzle: 1343 = 8*167 + 7 (q=167, r=7)
    int G;
    {
        const int L = blockIdx.x;
        const int xcd = L & 7;
        const int pos = L >> 3;
        G = (xcd < 7) ? xcd * 168 + pos : 1176 + pos;
    }
    const int mt = G / NT3;         // consecutive G share mt (A panel, frame overlap)
    const int nt = G - mt * NT3;

    // ---- staging bases
    const char* ablk = (const char*)apack + (size_t)mt * (64 * 8192)
                       + (wid << 11) + (lane << 4);

    const char* xpb = (const char*)xpad;
    const char* gb0;
    const char* gb1;
    {
        const int r0 = wid * 32 + (lane >> 2);            // B row, i=0 (i=1 -> +16)
        const int sc = (lane & 3) ^ ((r0 >> 1) & 3);      // same for r0+16
        int col = nt * 128 + r0;
        unsigned b = (unsigned)col / 626u;
        int tc = col - (int)b * 626;
        gb0 = xpb + ((size_t)b * XPAD_STRIDE + (size_t)tc * 512) * 2 + sc * 16;
        col += 16;
        b = (unsigned)col / 626u;
        tc = col - (int)b * 626;
        gb1 = xpb + ((size_t)b * XPAD_STRIDE + (size_t)tc * 512) * 2 + sc * 16;
    }

    // ---- ds_read bases: byte = row*64 + ((kq ^ (row>>1))&3)*16; (row>>1)&3 == (fr>>1)&3
    const unsigned swz = (unsigned)(((kq ^ (fr >> 1)) & 3) << 4);
    const unsigned offA_base = (unsigned)((wm * 64 + fr) * 64) + swz;
    const unsigned offB_base = 24576u + (unsigned)((wn * 64 + fr) * 64) + swz;

    f32x4 acc[4][4];
    #pragma unroll
    for (int m = 0; m < 4; ++m)
        #pragma unroll
        for (int n = 0; n < 4; ++n)
            acc[m][n] = f32x4{0.f, 0.f, 0.f, 0.f};

    bf16x8 pa0, pa1, pa2, pa3, pb0, pb1, pb2, pb3;   // set0 (even phases)
    bf16x8 qa0, qa1, qa2, qa3, qb0, qb1, qb2, qb3;   // set1 (odd phases)

    // ---- prologue: stage ph0->slot0, ph1->slot1; drain ph0; load set0 from slot0
    STGM(0, 0)
    STGM(1, 1)
    VM4
    __builtin_amdgcn_s_barrier();
    __builtin_amdgcn_sched_barrier(0);
    {
        const unsigned ab_ = offA_base;
        const unsigned bb_ = offB_base;
        pa0 = *(const bf16x8*)(lds + ab_);
        pa1 = *(const bf16x8*)(lds + ab_ + 1024);
        pa2 = *(const bf16x8*)(lds + ab_ + 2048);
        pa3 = *(const bf16x8*)(lds + ab_ + 3072);
        pb0 = *(const bf16x8*)(lds + bb_);
        pb1 = *(const bf16x8*)(lds + bb_ + 1024);
        pb2 = *(const bf16x8*)(lds + bb_ + 2048);
        pb3 = *(const bf16x8*)(lds + bb_ + 3072);
    }
    asm volatile("s_waitcnt lgkmcnt(0)" ::: "memory");
    __builtin_amdgcn_sched_barrier(0);

    // ---- main loop: phases 0..59 (period 6 = lcm(2 reg sets, 3 slots))
    #pragma unroll 1
    for (int i = 0; i < 10; ++i) {
        const int t = 6 * i;
        PHASE(1, STGM(t + 2, 2), VM4, pa0,pa1,pa2,pa3,pb0,pb1,pb2,pb3,
                                       qa0,qa1,qa2,qa3,qb0,qb1,qb2,qb3)   // p=t+0
        PHASE(2, STGM(t + 3, 0), VM4, qa0,qa1,qa2,qa3,qb0,qb1,qb2,qb3,
                                       pa0,pa1,pa2,pa3,pb0,pb1,pb2,pb3)   // p=t+1
        PHASE(0, STGM(t + 4, 1), VM4, pa0,pa1,pa2,pa3,pb0,pb1,pb2,pb3,
                                       qa0,qa1,qa2,qa3,qb0,qb1,qb2,qb3)   // p=t+2
        PHASE(1, STGM(t + 5, 2), VM4, qa0,qa1,qa2,qa3,qb0,qb1,qb2,qb3,
                                       pa0,pa1,pa2,pa3,pb0,pb1,pb2,pb3)   // p=t+3
        PHASE(2, STGM(t + 6, 0), VM4, pa0,pa1,pa2,pa3,pb0,pb1,pb2,pb3,
                                       qa0,qa1,qa2,qa3,qb0,qb1,qb2,qb3)   // p=t+4
        PHASE(0, STGM(t + 7, 1), VM4, qa0,qa1,qa2,qa3,qb0,qb1,qb2,qb3,
                                       pa0,pa1,pa2,pa3,pb0,pb1,pb2,pb3)   // p=t+5
    }
    // ---- tail: phases 60..63
    PHASE(1, STGM(62, 2), VM4, pa0,pa1,pa2,pa3,pb0,pb1,pb2,pb3,
                                qa0,qa1,qa2,qa3,qb0,qb1,qb2,qb3)          // p=60
    PHASE(2, STGM(63, 0), VM4, qa0,qa1,qa2,qa3,qb0,qb1,qb2,qb3,
                                pa0,pa1,pa2,pa3,pb0,pb1,pb2,pb3)          // p=61
    PHASE(0, , VM0,            pa0,pa1,pa2,pa3,pb0,pb1,pb2,pb3,
                                qa0,qa1,qa2,qa3,qb0,qb1,qb2,qb3)          // p=62
    __builtin_amdgcn_s_setprio(1);                                        // p=63
    MFMA_CLUSTER(qa0,qa1,qa2,qa3,qb0,qb1,qb2,qb3)
    __builtin_amdgcn_s_setprio(0);

    // ---- epilogue: C/D layout col = lane&15, row = kq*4 + j
    const size_t imag_base = (size_t)B_BATCH * NFREQ * T_OUT;
    #pragma unroll
    for (int n = 0; n < 4; ++n) {
        const int col = nt * 128 + wn * 64 + n * 16 + fr;
        if (col < NCOLS) {
            const unsigned b = (unsigned)col / 626u;
            const int tc = col - (int)b * 626;
            const size_t colbase = (size_t)b * NFREQ * T_OUT + (size_t)tc;
            #pragma unroll
            for (int m = 0; m < 4; ++m) {
                #pragma unroll
                for (int j = 0; j < 4; ++j) {
                    const int grow = mt * 128 + wm * 64 + m * 16 + kq * 4 + j;
                    if (grow < M_ROWS) {
                        const size_t off = (grow < NFREQ)
                            ? colbase + (size_t)grow * T_OUT
                            : imag_base + colbase + (size_t)(grow - NFREQ) * T_OUT;
                        out[off] = acc[m][n][j];
                    }
                }
            }
        }
    }
}

// ---------------- no-workspace fallback (round-1 structure) ----------------
__device__ __forceinline__ unsigned lds_off_fb(int row, int kbyte) {
    return (unsigned)(row * 128 + (kbyte ^ ((row & 7) << 4)));
}

__global__ __launch_bounds__(256) void stft_gemm_fb(
    const float* __restrict__ x,
    const float* __restrict__ wre,
    const float* __restrict__ wim,
    float* __restrict__ out)
{
    __shared__ __align__(16) unsigned char ldsA[128 * 128];
    __shared__ __align__(16) unsigned char ldsB[128 * 128];

    const int tid  = threadIdx.x;
    const int lane = tid & 63;
    const int wid  = tid >> 6;
    const int wmf  = wid >> 1;
    const int wnf  = wid & 1;

    const int bid = blockIdx.x;
    const int b   = bid / (17 * 5);
    const int rem = bid % (17 * 5);
    const int mt  = rem / 5;
    const int nt  = rem % 5;

    const int row0 = mt * 128;
    const int col0 = nt * 128;
    const float* xb = x + (size_t)b * XLEN;

    const int c4 = (tid & 15) * 4;
    const int r0 = tid >> 4;

    f32x4 acc[4][4];
    #pragma unroll
    for (int m = 0; m < 4; ++m)
        #pragma unroll
        for (int n = 0; n < 4; ++n)
            acc[m][n] = f32x4{0.f, 0.f, 0.f, 0.f};

    const int fr = lane & 15;
    const int kq = lane >> 4;

    for (int k0 = 0; k0 < NFFT; k0 += 64) {
        bf16x4 sa[8], sb[8];
        #pragma unroll
        for (int rr = 0; rr < 8; ++rr) {
            const int row  = rr * 16 + r0;
            const int grow = row0 + row;
            float4 v = make_float4(0.f, 0.f, 0.f, 0.f);
            if (grow < M_ROWS) {
                const float* wsrc = (grow < NFREQ)
                    ? (wre + (size_t)grow * NFFT)
                    : (wim + (size_t)(grow - NFREQ) * NFFT);
                v = *reinterpret_cast<const float4*>(wsrc + k0 + c4);
            }
            sa[rr].x = (__bf16)v.x; sa[rr].y = (__bf16)v.y;
            sa[rr].z = (__bf16)v.z; sa[rr].w = (__bf16)v.w;
        }
        #pragma unroll
        for (int rr = 0; rr < 8; ++rr) {
            const int trow = rr * 16 + r0;
            const int t    = col0 + trow;
            float4 v = make_float4(0.f, 0.f, 0.f, 0.f);
            if (t < T_OUT) {
                const int pos = t * HOP + k0 + c4 - PADW;
                if (pos >= 0 && pos <= XLEN - 4) {
                    v = *reinterpret_cast<const float4*>(xb + pos);
                } else {
                    float tmp[4];
                    #pragma unroll
                    for (int e = 0; e < 4; ++e) {
                        int p = pos + e;
                        p = (p < 0) ? -p : p;
                        p = (p >= XLEN) ? (2 * XLEN - 2 - p) : p;
                        tmp[e] = xb[p];
                    }
                    v = make_float4(tmp[0], tmp[1], tmp[2], tmp[3]);
                }
            }
            sb[rr].x = (__bf16)v.x; sb[rr].y = (__bf16)v.y;
            sb[rr].z = (__bf16)v.z; sb[rr].w = (__bf16)v.w;
        }
        __syncthreads();
        #pragma unroll
        for (int rr = 0; rr < 8; ++rr) {
            const int row = rr * 16 + r0;
            *reinterpret_cast<bf16x4*>(ldsA + lds_off_fb(row, c4 * 2)) = sa[rr];
            *reinterpret_cast<bf16x4*>(ldsB + lds_off_fb(row, c4 * 2)) = sb[rr];
        }
        __syncthreads();
        #pragma unroll
        for (int kk = 0; kk < 2; ++kk) {
            const int kbyte = kk * 64 + kq * 16;
            bf16x8 af[4], bfv[4];
            #pragma unroll
            for (int m = 0; m < 4; ++m)
                af[m] = *reinterpret_cast<const bf16x8*>(
                    ldsA + lds_off_fb(wmf * 64 + m * 16 + fr, kbyte));
            #pragma unroll
            for (int n = 0; n < 4; ++n)
                bfv[n] = *reinterpret_cast<const bf16x8*>(
                    ldsB + lds_off_fb(wnf * 64 + n * 16 + fr, kbyte));
            #pragma unroll
            for (int m = 0; m < 4; ++m)
                #pragma unroll
                for (int n = 0; n < 4; ++n)
                    acc[m][n] = MFMA16(af[m], bfv[n], acc[m][n], 0, 0, 0);
        }
    }

    const size_t imag_base = (size_t)B_BATCH * NFREQ * T_OUT;
    #pragma unroll
    for (int m = 0; m < 4; ++m) {
        #pragma unroll
        for (int n = 0; n < 4; ++n) {
            #pragma unroll
            for (int j = 0; j < 4; ++j) {
                const int grow = row0 + wmf * 64 + m * 16 + kq * 4 + j;
                const int gcol = col0 + wnf * 64 + n * 16 + fr;
                if (grow < M_ROWS && gcol < T_OUT) {
                    size_t off;
                    if (grow < NFREQ)
                        off = ((size_t)b * NFREQ + grow) * T_OUT + gcol;
                    else
                        off = imag_base + ((size_t)b * NFREQ + (grow - NFREQ)) * T_OUT + gcol;
                    out[off] = acc[m][n][j];
                }
            }
        }
    }
}

extern "C" void kernel_launch(void* const* d_in, const int* in_sizes, int n_in,
                              void* d_out, int out_size, void* d_ws, size_t ws_size,
                              hipStream_t stream) {
    const float* x   = (const float*)d_in[0];
    const float* wre = (const float*)d_in[1];
    const float* wim = (const float*)d_in[2];
    float* out = (float*)d_out;

    if (ws_size < WS_NEEDED) {
        stft_gemm_fb<<<dim3(B_BATCH * 17 * 5), 256, 0, stream>>>(x, wre, wim, out);
        return;
    }

    __bf16* apack = (__bf16*)d_ws;
    __bf16* xpad  = (__bf16*)((char*)d_ws + APACK_BYTES);

    prep_w<<<dim3(557056 / 256), 256, 0, stream>>>(wre, wim, apack);
    prep_x<<<dim3(((B_BATCH + 1) * (XPAD_STRIDE / 8) + 255) / 256), 256, 0, stream>>>(x, xpad);
    stft_gemm5<<<dim3(NBLK), 256, 0, stream>>>(apack, xpad, out);
}

// Round 6
// 135.962 us; speedup vs baseline: 1.1223x; 1.1223x over previous
//
#include <hip/hip_runtime.h>

#define B_BATCH 16
#define XLEN    320000
#define NFFT    2048
#define HOP     512
#define PADW    1024
#define NFREQ   1025
#define T_OUT   626
#define M_ROWS  2050
#define NCOLS   (B_BATCH * T_OUT)          // 10016
#define MT2     17                          // ceil(2050/128)
#define NT2     40                          // ceil(10016/256)
#define NBLK    (MT2 * NT2)                 // 680 = 8*85
#define KT2     32                          // 2048/64

#define XPAD_LEN    322048                  // XLEN + 2*PADW
#define XPAD_STRIDE 330240
#define APACK_BYTES ((size_t)MT2 * 64 * 8192)                  // 8,912,896
#define XPAD_BYTES  ((size_t)(B_BATCH + 1) * XPAD_STRIDE * 2)  // 11,228,160 (slot 16 = zeros)
#define WS_NEEDED   (APACK_BYTES + XPAD_BYTES)

typedef __bf16 bf16x8 __attribute__((ext_vector_type(8)));
typedef __bf16 bf16x4 __attribute__((ext_vector_type(4)));
typedef float  f32x4  __attribute__((ext_vector_type(4)));

__device__ __forceinline__ void gload_lds16(const void* g, void* l) {
    __builtin_amdgcn_global_load_lds(
        (const __attribute__((address_space(1))) unsigned int*)g,
        (__attribute__((address_space(3))) unsigned int*)l,
        16, 0, 0);
}

// ---------------- prep A: weights fp32 -> bf16, packed in exact LDS-slot layout ----
// Half-slot ph = kt*2+ks (64 per mt), 8 KB each: byte row*64 + scell*16 holds
// W[mt*128+row][ph*32 + (((scell ^ (row>>1)) & 3)<<3) + e], e in [0,8).
__global__ __launch_bounds__(256) void prep_w(
    const float* __restrict__ wre, const float* __restrict__ wim,
    __bf16* __restrict__ apack)
{
    const int gid   = blockIdx.x * 256 + threadIdx.x;  // 557056 total
    const int scell = gid & 3;
    const int row   = (gid >> 2) & 127;
    const int ph    = (gid >> 9) & 63;
    const int mt    = gid >> 15;

    const int grow = mt * 128 + row;
    const int k    = ph * 32 + (((scell ^ (row >> 1)) & 3) << 3);

    bf16x8 v = bf16x8{};
    if (grow < M_ROWS) {
        const float* src = (grow < NFREQ)
            ? (wre + (size_t)grow * NFFT + k)
            : (wim + (size_t)(grow - NFREQ) * NFFT + k);
        const float4 a = *reinterpret_cast<const float4*>(src);
        const float4 b = *reinterpret_cast<const float4*>(src + 4);
        v[0] = (__bf16)a.x; v[1] = (__bf16)a.y; v[2] = (__bf16)a.z; v[3] = (__bf16)a.w;
        v[4] = (__bf16)b.x; v[5] = (__bf16)b.y; v[6] = (__bf16)b.z; v[7] = (__bf16)b.w;
    }
    *reinterpret_cast<bf16x8*>(apack + (size_t)gid * 8) = v;
}

// ---------------- prep B: reflect-padded signal fp32 -> bf16 (slot 16 = zeros) ----
__global__ __launch_bounds__(256) void prep_x(
    const float* __restrict__ x, __bf16* __restrict__ xpad)
{
    const int gid = blockIdx.x * 256 + threadIdx.x;
    if (gid >= (B_BATCH + 1) * (XPAD_STRIDE / 8)) return;
    const int b  = gid / (XPAD_STRIDE / 8);
    const int i0 = (gid - b * (XPAD_STRIDE / 8)) * 8;

    bf16x8 v = bf16x8{};
    if (b < B_BATCH) {
        const float* xb = x + (size_t)b * XLEN;
        const int pos0 = i0 - PADW;
        if (pos0 >= 0 && pos0 + 8 <= XLEN) {
            const float4 a = *reinterpret_cast<const float4*>(xb + pos0);
            const float4 c = *reinterpret_cast<const float4*>(xb + pos0 + 4);
            v[0] = (__bf16)a.x; v[1] = (__bf16)a.y; v[2] = (__bf16)a.z; v[3] = (__bf16)a.w;
            v[4] = (__bf16)c.x; v[5] = (__bf16)c.y; v[6] = (__bf16)c.z; v[7] = (__bf16)c.w;
        } else {
            #pragma unroll
            for (int e = 0; e < 8; ++e) {
                const int i = i0 + e;
                if (i >= XPAD_LEN) { v[e] = (__bf16)0.f; continue; }
                int p = i - PADW;
                p = (p < 0) ? -p : p;
                p = (p >= XLEN) ? (2 * XLEN - 2 - p) : p;
                v[e] = (__bf16)xb[p];
            }
        }
    }
    *reinterpret_cast<bf16x8*>(xpad + (size_t)b * XPAD_STRIDE + i0) = v;
}

// ---------------- main GEMM: 128x256 block, 4 waves of 64x128, reg-dbuf pipeline ----
// 64 phases (K=32 each). Phase p: STG(p+2) -> vmcnt(6) (drains STG(p+1)) ->
// barrier -> ds_read phase-(p+1) frags into NXT arrays -> 32 MFMA on CUR ->
// lgkmcnt(0). LDS = 3 slots x (A 8K + B 16K) = 72 KB -> 2 blocks/CU.

#define MFMA16 __builtin_amdgcn_mfma_f32_16x16x32_bf16

#define VM6 asm volatile("s_waitcnt vmcnt(6)" ::: "memory");
#define VM0 asm volatile("s_waitcnt vmcnt(0)" ::: "memory");

#define STGM(PH_, SLOT_) {                                                        \
    const char* as_ = ablk + ((size_t)(PH_) << 13);                               \
    unsigned char* ad_ = lds + ((SLOT_) << 13) + (wid << 10);                     \
    gload_lds16(as_, ad_);                                                        \
    gload_lds16(as_ + 4096, ad_ + 4096);                                          \
    const int ko_ = (PH_) << 6;                                                   \
    unsigned char* bd_ = lds + 24576 + ((SLOT_) << 14) + (wid << 10);             \
    gload_lds16(gb0 + ko_, bd_);                                                  \
    gload_lds16(gb1 + ko_, bd_ + 4096);                                           \
    gload_lds16(gb2 + ko_, bd_ + 8192);                                           \
    gload_lds16(gb3 + ko_, bd_ + 12288);                                          \
}

#define DSRD(SLN_, FA_, FB_) {                                                    \
    const unsigned ab_ = ((unsigned)(SLN_) << 13) + offA_base;                    \
    const unsigned bb_ = 24576u + ((unsigned)(SLN_) << 14) + offB_base;           \
    _Pragma("unroll")                                                             \
    for (int m_ = 0; m_ < 4; ++m_)                                                \
        FA_[m_] = *(const bf16x8*)(lds + ab_ + (m_ << 10));                       \
    _Pragma("unroll")                                                             \
    for (int n_ = 0; n_ < 8; ++n_)                                                \
        FB_[n_] = *(const bf16x8*)(lds + bb_ + (n_ << 10));                       \
}

#define CLUSTER(FA_, FB_) {                                                       \
    __builtin_amdgcn_s_setprio(1);                                                \
    _Pragma("unroll")                                                             \
    for (int m_ = 0; m_ < 4; ++m_)                                                \
        _Pragma("unroll")                                                         \
        for (int n_ = 0; n_ < 8; ++n_)                                            \
            acc[m_][n_] = MFMA16(FA_[m_], FB_[n_], acc[m_][n_], 0, 0, 0);         \
    __builtin_amdgcn_s_setprio(0);                                                \
}

#define PHASE(SLN_, STG_, VMW_, CFA_, CFB_, NFA_, NFB_) {                         \
    STG_                                                                          \
    VMW_                                                                          \
    __builtin_amdgcn_s_barrier();                                                 \
    __builtin_amdgcn_sched_barrier(0);                                            \
    DSRD(SLN_, NFA_, NFB_)                                                        \
    CLUSTER(CFA_, CFB_)                                                           \
    asm volatile("s_waitcnt lgkmcnt(0)" ::: "memory");                            \
    __builtin_amdgcn_sched_barrier(0);                                            \
}

__global__ __launch_bounds__(256, 2) void stft_gemm6(
    const __bf16* __restrict__ apack,
    const __bf16* __restrict__ xpad,
    float* __restrict__ out)
{
    __shared__ __align__(16) unsigned char lds[73728];   // 72 KB -> 2 blocks/CU

    const int tid  = threadIdx.x;
    const int lane = tid & 63;
    const int wid  = tid >> 6;   // 0..3
    const int wm   = wid >> 1;   // 0..1  (64-row panel)
    const int wn   = wid & 1;    // 0..1  (128-col panel)
    const int fr   = lane & 15;
    const int kq   = lane >> 4;

    // bijective XCD-chunked swizzle: 680 = 8 * 85; consecutive orig share nt (B panel)
    const int orig = (blockIdx.x & 7) * 85 + (blockIdx.x >> 3);
    const int nt = orig / MT2;
    const int mt = orig % MT2;

    // ---- staging bases
    const char* ablk = (const char*)apack + (size_t)mt * (64 * 8192) + (size_t)tid * 16;

    const char* xpb = (const char*)xpad;
    const char* gb0; const char* gb1; const char* gb2; const char* gb3;
    {
        const int r0 = tid >> 2;                         // 0..63; loads rows r0+64j
        const int sc = (tid & 3) ^ ((r0 >> 1) & 3);      // same for all j (64/2%4==0)
        #pragma unroll
        for (int j = 0; j < 4; ++j) {
            const int col = nt * 256 + r0 + 64 * j;
            const unsigned b = (unsigned)col / 626u;
            const int tc = col - (int)b * 626;
            const char* p = xpb + ((size_t)b * XPAD_STRIDE + (size_t)tc * 512) * 2 + sc * 16;
            if (j == 0) gb0 = p; else if (j == 1) gb1 = p;
            else if (j == 2) gb2 = p; else gb3 = p;
        }
    }

    // ---- ds_read bases: byte = row*64 + ((kq ^ (row>>1))&3)*16
    const unsigned swz = (unsigned)(((kq ^ (fr >> 1)) & 3) << 4);
    const unsigned offA_base = (unsigned)((wm * 64 + fr) * 64) + swz;
    const unsigned offB_base = (unsigned)((wn * 128 + fr) * 64) + swz;

    f32x4 acc[4][8];
    #pragma unroll
    for (int m = 0; m < 4; ++m)
        #pragma unroll
        for (int n = 0; n < 8; ++n)
            acc[m][n] = f32x4{0.f, 0.f, 0.f, 0.f};

    bf16x8 faP[4], fbP[8], faQ[4], fbQ[8];

    // ---- prologue: stage ph0->slot0, ph1->slot1 (12 out); VM6 drains ph0
    STGM(0, 0)
    STGM(1, 1)
    VM6
    __builtin_amdgcn_s_barrier();
    __builtin_amdgcn_sched_barrier(0);
    DSRD(0, faP, fbP)
    asm volatile("s_waitcnt lgkmcnt(0)" ::: "memory");
    __builtin_amdgcn_sched_barrier(0);

    // ---- main loop: phases 0..59 (period 6 = lcm(2 reg sets, 3 slots))
    #pragma unroll 1
    for (int i = 0; i < 10; ++i) {
        const int t = 6 * i;
        PHASE(1, STGM(t + 2, 2), VM6, faP, fbP, faQ, fbQ)   // p=t+0
        PHASE(2, STGM(t + 3, 0), VM6, faQ, fbQ, faP, fbP)   // p=t+1
        PHASE(0, STGM(t + 4, 1), VM6, faP, fbP, faQ, fbQ)   // p=t+2
        PHASE(1, STGM(t + 5, 2), VM6, faQ, fbQ, faP, fbP)   // p=t+3
        PHASE(2, STGM(t + 6, 0), VM6, faP, fbP, faQ, fbQ)   // p=t+4
        PHASE(0, STGM(t + 7, 1), VM6, faQ, fbQ, faP, fbP)   // p=t+5
    }
    // ---- tail: phases 60..63
    PHASE(1, STGM(62, 2), VM6, faP, fbP, faQ, fbQ)          // p=60
    PHASE(2, STGM(63, 0), VM6, faQ, fbQ, faP, fbP)          // p=61
    PHASE(0, , VM0,            faP, fbP, faQ, fbQ)          // p=62
    CLUSTER(faQ, fbQ)                                        // p=63

    // ---- epilogue: C/D layout col = lane&15, row = kq*4 + j
    const size_t imag_base = (size_t)B_BATCH * NFREQ * T_OUT;
    #pragma unroll
    for (int n = 0; n < 8; ++n) {
        const int col = nt * 256 + wn * 128 + n * 16 + fr;
        if (col < NCOLS) {
            const unsigned b = (unsigned)col / 626u;
            const int tc = col - (int)b * 626;
            const size_t colbase = (size_t)b * NFREQ * T_OUT + (size_t)tc;
            #pragma unroll
            for (int m = 0; m < 4; ++m) {
                #pragma unroll
                for (int j = 0; j < 4; ++j) {
                    const int grow = mt * 128 + wm * 64 + m * 16 + kq * 4 + j;
                    if (grow < M_ROWS) {
                        const size_t off = (grow < NFREQ)
                            ? colbase + (size_t)grow * T_OUT
                            : imag_base + colbase + (size_t)(grow - NFREQ) * T_OUT;
                        out[off] = acc[m][n][j];
                    }
                }
            }
        }
    }
}

// ---------------- no-workspace fallback (round-1 structure) ----------------
__device__ __forceinline__ unsigned lds_off_fb(int row, int kbyte) {
    return (unsigned)(row * 128 + (kbyte ^ ((row & 7) << 4)));
}

__global__ __launch_bounds__(256) void stft_gemm_fb(
    const float* __restrict__ x,
    const float* __restrict__ wre,
    const float* __restrict__ wim,
    float* __restrict__ out)
{
    __shared__ __align__(16) unsigned char ldsA[128 * 128];
    __shared__ __align__(16) unsigned char ldsB[128 * 128];

    const int tid  = threadIdx.x;
    const int lane = tid & 63;
    const int wid  = tid >> 6;
    const int wmf  = wid >> 1;
    const int wnf  = wid & 1;

    const int bid = blockIdx.x;
    const int b   = bid / (17 * 5);
    const int rem = bid % (17 * 5);
    const int mt  = rem / 5;
    const int nt  = rem % 5;

    const int row0 = mt * 128;
    const int col0 = nt * 128;
    const float* xb = x + (size_t)b * XLEN;

    const int c4 = (tid & 15) * 4;
    const int r0 = tid >> 4;

    f32x4 acc[4][4];
    #pragma unroll
    for (int m = 0; m < 4; ++m)
        #pragma unroll
        for (int n = 0; n < 4; ++n)
            acc[m][n] = f32x4{0.f, 0.f, 0.f, 0.f};

    const int fr = lane & 15;
    const int kq = lane >> 4;

    for (int k0 = 0; k0 < NFFT; k0 += 64) {
        bf16x4 sa[8], sb[8];
        #pragma unroll
        for (int rr = 0; rr < 8; ++rr) {
            const int row  = rr * 16 + r0;
            const int grow = row0 + row;
            float4 v = make_float4(0.f, 0.f, 0.f, 0.f);
            if (grow < M_ROWS) {
                const float* wsrc = (grow < NFREQ)
                    ? (wre + (size_t)grow * NFFT)
                    : (wim + (size_t)(grow - NFREQ) * NFFT);
                v = *reinterpret_cast<const float4*>(wsrc + k0 + c4);
            }
            sa[rr].x = (__bf16)v.x; sa[rr].y = (__bf16)v.y;
            sa[rr].z = (__bf16)v.z; sa[rr].w = (__bf16)v.w;
        }
        #pragma unroll
        for (int rr = 0; rr < 8; ++rr) {
            const int trow = rr * 16 + r0;
            const int t    = col0 + trow;
            float4 v = make_float4(0.f, 0.f, 0.f, 0.f);
            if (t < T_OUT) {
                const int pos = t * HOP + k0 + c4 - PADW;
                if (pos >= 0 && pos <= XLEN - 4) {
                    v = *reinterpret_cast<const float4*>(xb + pos);
                } else {
                    float tmp[4];
                    #pragma unroll
                    for (int e = 0; e < 4; ++e) {
                        int p = pos + e;
                        p = (p < 0) ? -p : p;
                        p = (p >= XLEN) ? (2 * XLEN - 2 - p) : p;
                        tmp[e] = xb[p];
                    }
                    v = make_float4(tmp[0], tmp[1], tmp[2], tmp[3]);
                }
            }
            sb[rr].x = (__bf16)v.x; sb[rr].y = (__bf16)v.y;
            sb[rr].z = (__bf16)v.z; sb[rr].w = (__bf16)v.w;
        }
        __syncthreads();
        #pragma unroll
        for (int rr = 0; rr < 8; ++rr) {
            const int row = rr * 16 + r0;
            *reinterpret_cast<bf16x4*>(ldsA + lds_off_fb(row, c4 * 2)) = sa[rr];
            *reinterpret_cast<bf16x4*>(ldsB + lds_off_fb(row, c4 * 2)) = sb[rr];
        }
        __syncthreads();
        #pragma unroll
        for (int kk = 0; kk < 2; ++kk) {
            const int kbyte = kk * 64 + kq * 16;
            bf16x8 af[4], bfv[4];
            #pragma unroll
            for (int m = 0; m < 4; ++m)
                af[m] = *reinterpret_cast<const bf16x8*>(
                    ldsA + lds_off_fb(wmf * 64 + m * 16 + fr, kbyte));
            #pragma unroll
            for (int n = 0; n < 4; ++n)
                bfv[n] = *reinterpret_cast<const bf16x8*>(
                    ldsB + lds_off_fb(wnf * 64 + n * 16 + fr, kbyte));
            #pragma unroll
            for (int m = 0; m < 4; ++m)
                #pragma unroll
                for (int n = 0; n < 4; ++n)
                    acc[m][n] = MFMA16(af[m], bfv[n], acc[m][n], 0, 0, 0);
        }
    }

    const size_t imag_base = (size_t)B_BATCH * NFREQ * T_OUT;
    #pragma unroll
    for (int m = 0; m < 4; ++m) {
        #pragma unroll
        for (int n = 0; n < 4; ++n) {
            #pragma unroll
            for (int j = 0; j < 4; ++j) {
                const int grow = row0 + wmf * 64 + m * 16 + kq * 4 + j;
                const int gcol = col0 + wnf * 64 + n * 16 + fr;
                if (grow < M_ROWS && gcol < T_OUT) {
                    size_t off;
                    if (grow < NFREQ)
                        off = ((size_t)b * NFREQ + grow) * T_OUT + gcol;
                    else
                        off = imag_base + ((size_t)b * NFREQ + (grow - NFREQ)) * T_OUT + gcol;
                    out[off] = acc[m][n][j];
                }
            }
        }
    }
}

extern "C" void kernel_launch(void* const* d_in, const int* in_sizes, int n_in,
                              void* d_out, int out_size, void* d_ws, size_t ws_size,
                              hipStream_t stream) {
    const float* x   = (const float*)d_in[0];
    const float* wre = (const float*)d_in[1];
    const float* wim = (const float*)d_in[2];
    float* out = (float*)d_out;

    if (ws_size < WS_NEEDED) {
        stft_gemm_fb<<<dim3(B_BATCH * 17 * 5), 256, 0, stream>>>(x, wre, wim, out);
        return;
    }

    __bf16* apack = (__bf16*)d_ws;
    __bf16* xpad  = (__bf16*)((char*)d_ws + APACK_BYTES);

    prep_w<<<dim3(557056 / 256), 256, 0, stream>>>(wre, wim, apack);
    prep_x<<<dim3(((B_BATCH + 1) * (XPAD_STRIDE / 8) + 255) / 256), 256, 0, stream>>>(x, xpad);
    stft_gemm6<<<dim3(NBLK), 256, 0, stream>>>(apack, xpad, out);
}

// Round 7
// 113.715 us; speedup vs baseline: 1.3418x; 1.1956x over previous
//
#include <hip/hip_runtime.h>

#define B_BATCH 16
#define XLEN    320000
#define NFFT    2048
#define HOP     512
#define PADW    1024
#define NFREQ   1025
#define T_OUT   626
#define M_ROWS  2050
#define NCOLS   (B_BATCH * T_OUT)          // 10016
#define MT2     17                          // ceil(2050/128)
#define NT2     40                          // ceil(10016/256)
#define NBLK    (MT2 * NT2)                 // 680 = 8*85
#define KT2     32                          // 2048/64

#define XPAD_LEN    322048                  // XLEN + 2*PADW
#define XPAD_STRIDE 330240
#define APACK_BYTES ((size_t)MT2 * 64 * 8192)                  // 8,912,896
#define XPAD_BYTES  ((size_t)(B_BATCH + 1) * XPAD_STRIDE * 2)  // 11,228,160 (slot 16 = zeros)
#define WS_NEEDED   (APACK_BYTES + XPAD_BYTES)

typedef __bf16 bf16x8 __attribute__((ext_vector_type(8)));
typedef __bf16 bf16x4 __attribute__((ext_vector_type(4)));
typedef float  f32x4  __attribute__((ext_vector_type(4)));

__device__ __forceinline__ void gload_lds16(const void* g, void* l) {
    __builtin_amdgcn_global_load_lds(
        (const __attribute__((address_space(1))) unsigned int*)g,
        (__attribute__((address_space(3))) unsigned int*)l,
        16, 0, 0);
}

// ---------------- prep A: weights fp32 -> bf16, packed in exact LDS-slot layout ----
// Half-slot ph = kt*2+ks (64 per mt), 8 KB each: byte row*64 + scell*16 holds
// W[mt*128+row][ph*32 + (((scell ^ (row>>1)) & 3)<<3) + e], e in [0,8).
__global__ __launch_bounds__(256) void prep_w(
    const float* __restrict__ wre, const float* __restrict__ wim,
    __bf16* __restrict__ apack)
{
    const int gid   = blockIdx.x * 256 + threadIdx.x;  // 557056 total
    const int scell = gid & 3;
    const int row   = (gid >> 2) & 127;
    const int ph    = (gid >> 9) & 63;
    const int mt    = gid >> 15;

    const int grow = mt * 128 + row;
    const int k    = ph * 32 + (((scell ^ (row >> 1)) & 3) << 3);

    bf16x8 v = bf16x8{};
    if (grow < M_ROWS) {
        const float* src = (grow < NFREQ)
            ? (wre + (size_t)grow * NFFT + k)
            : (wim + (size_t)(grow - NFREQ) * NFFT + k);
        const float4 a = *reinterpret_cast<const float4*>(src);
        const float4 b = *reinterpret_cast<const float4*>(src + 4);
        v[0] = (__bf16)a.x; v[1] = (__bf16)a.y; v[2] = (__bf16)a.z; v[3] = (__bf16)a.w;
        v[4] = (__bf16)b.x; v[5] = (__bf16)b.y; v[6] = (__bf16)b.z; v[7] = (__bf16)b.w;
    }
    *reinterpret_cast<bf16x8*>(apack + (size_t)gid * 8) = v;
}

// ---------------- prep B: reflect-padded signal fp32 -> bf16 (slot 16 = zeros) ----
__global__ __launch_bounds__(256) void prep_x(
    const float* __restrict__ x, __bf16* __restrict__ xpad)
{
    const int gid = blockIdx.x * 256 + threadIdx.x;
    if (gid >= (B_BATCH + 1) * (XPAD_STRIDE / 8)) return;
    const int b  = gid / (XPAD_STRIDE / 8);
    const int i0 = (gid - b * (XPAD_STRIDE / 8)) * 8;

    bf16x8 v = bf16x8{};
    if (b < B_BATCH) {
        const float* xb = x + (size_t)b * XLEN;
        const int pos0 = i0 - PADW;
        if (pos0 >= 0 && pos0 + 8 <= XLEN) {
            const float4 a = *reinterpret_cast<const float4*>(xb + pos0);
            const float4 c = *reinterpret_cast<const float4*>(xb + pos0 + 4);
            v[0] = (__bf16)a.x; v[1] = (__bf16)a.y; v[2] = (__bf16)a.z; v[3] = (__bf16)a.w;
            v[4] = (__bf16)c.x; v[5] = (__bf16)c.y; v[6] = (__bf16)c.z; v[7] = (__bf16)c.w;
        } else {
            #pragma unroll
            for (int e = 0; e < 8; ++e) {
                const int i = i0 + e;
                if (i >= XPAD_LEN) { v[e] = (__bf16)0.f; continue; }
                int p = i - PADW;
                p = (p < 0) ? -p : p;
                p = (p >= XLEN) ? (2 * XLEN - 2 - p) : p;
                v[e] = (__bf16)xb[p];
            }
        }
    }
    *reinterpret_cast<bf16x8*>(xpad + (size_t)b * XPAD_STRIDE + i0) = v;
}

// ---------------- main GEMM: r4 geometry, reads hoisted off the critical path ----
// 512 thr (8 waves of 64x64), BM=128 BN=256, 3 slots x (A 8K + B 16K) = 72 KB.
// Phase p: DSRD(slot p%3) -> STG(p+2 -> slot (p+2)%3) -> vmcnt(3) (drains
// STG(p+1)) -> barrier -> lgkmcnt(0) -> 16 MFMA. ds_read latency hides under
// the vmcnt drain + barrier + other waves' MFMA.

#define MFMA16 __builtin_amdgcn_mfma_f32_16x16x32_bf16

#define VM3 asm volatile("s_waitcnt vmcnt(3)" ::: "memory");
#define VM0 asm volatile("s_waitcnt vmcnt(0)" ::: "memory");

#define STG(PH_, SLOT_) {                                                         \
    gload_lds16(ablk + ((size_t)(PH_) << 13),                                     \
                lds + ((SLOT_) << 13) + (wid << 10));                             \
    {                                                                             \
        const int ko_ = (PH_) << 6;                                               \
        unsigned char* d_ = lds + 24576 + ((SLOT_) << 14) + (wid << 10);          \
        gload_lds16(gb0 + ko_, d_);                                               \
        gload_lds16(gb1 + ko_, d_ + 8192);                                        \
    }                                                                             \
}

#define PH(SLOT_, STG_, VMW_) {                                                   \
    bf16x8 a0, a1, a2, a3, b0, b1, b2, b3;                                        \
    {                                                                             \
        const unsigned ab_ = ((unsigned)(SLOT_) << 13) + offA_base;               \
        const unsigned bb_ = 24576u + ((unsigned)(SLOT_) << 14) + offB_base;      \
        a0 = *(const bf16x8*)(lds + ab_);                                         \
        a1 = *(const bf16x8*)(lds + ab_ + 1024);                                  \
        a2 = *(const bf16x8*)(lds + ab_ + 2048);                                  \
        a3 = *(const bf16x8*)(lds + ab_ + 3072);                                  \
        b0 = *(const bf16x8*)(lds + bb_);                                         \
        b1 = *(const bf16x8*)(lds + bb_ + 1024);                                  \
        b2 = *(const bf16x8*)(lds + bb_ + 2048);                                  \
        b3 = *(const bf16x8*)(lds + bb_ + 3072);                                  \
    }                                                                             \
    STG_                                                                          \
    VMW_                                                                          \
    __builtin_amdgcn_s_barrier();                                                 \
    asm volatile("s_waitcnt lgkmcnt(0)" ::: "memory");                            \
    __builtin_amdgcn_sched_barrier(0);                                            \
    __builtin_amdgcn_s_setprio(1);                                                \
    acc[0][0] = MFMA16(a0, b0, acc[0][0], 0, 0, 0);                               \
    acc[0][1] = MFMA16(a0, b1, acc[0][1], 0, 0, 0);                               \
    acc[0][2] = MFMA16(a0, b2, acc[0][2], 0, 0, 0);                               \
    acc[0][3] = MFMA16(a0, b3, acc[0][3], 0, 0, 0);                               \
    acc[1][0] = MFMA16(a1, b0, acc[1][0], 0, 0, 0);                               \
    acc[1][1] = MFMA16(a1, b1, acc[1][1], 0, 0, 0);                               \
    acc[1][2] = MFMA16(a1, b2, acc[1][2], 0, 0, 0);                               \
    acc[1][3] = MFMA16(a1, b3, acc[1][3], 0, 0, 0);                               \
    acc[2][0] = MFMA16(a2, b0, acc[2][0], 0, 0, 0);                               \
    acc[2][1] = MFMA16(a2, b1, acc[2][1], 0, 0, 0);                               \
    acc[2][2] = MFMA16(a2, b2, acc[2][2], 0, 0, 0);                               \
    acc[2][3] = MFMA16(a2, b3, acc[2][3], 0, 0, 0);                               \
    acc[3][0] = MFMA16(a3, b0, acc[3][0], 0, 0, 0);                               \
    acc[3][1] = MFMA16(a3, b1, acc[3][1], 0, 0, 0);                               \
    acc[3][2] = MFMA16(a3, b2, acc[3][2], 0, 0, 0);                               \
    acc[3][3] = MFMA16(a3, b3, acc[3][3], 0, 0, 0);                               \
    __builtin_amdgcn_s_setprio(0);                                                \
}

__global__ __launch_bounds__(512, 4) void stft_gemm7(
    const __bf16* __restrict__ apack,
    const __bf16* __restrict__ xpad,
    float* __restrict__ out)
{
    __shared__ __align__(16) unsigned char lds[73728];   // 72 KB -> 2 blocks/CU

    const int tid  = threadIdx.x;
    const int lane = tid & 63;
    const int wid  = tid >> 6;   // 0..7
    const int wm   = wid >> 2;   // 0..1
    const int wn   = wid & 3;    // 0..3
    const int fr   = lane & 15;
    const int kq   = lane >> 4;

    // bijective XCD-chunked swizzle: 680 = 8 * 85; consecutive orig share nt
    const int orig = (blockIdx.x & 7) * 85 + (blockIdx.x >> 3);
    const int nt = orig / MT2;
    const int mt = orig % MT2;

    // ---- staging bases
    const char* ablk = (const char*)apack + (size_t)mt * (64 * 8192) + (size_t)tid * 16;

    const char* xpb = (const char*)xpad;
    const char* gb0;
    const char* gb1;
    {
        const int r0 = tid >> 2;                         // 0..127; rows r0, r0+128
        const int sc = (tid & 3) ^ ((r0 >> 1) & 3);      // same for r0+128 (128/2%4==0)
        int col = nt * 256 + r0;
        unsigned b = (unsigned)col / 626u;
        int tc = col - (int)b * 626;
        gb0 = xpb + ((size_t)b * XPAD_STRIDE + (size_t)tc * 512) * 2 + sc * 16;
        col += 128;
        b = (unsigned)col / 626u;
        tc = col - (int)b * 626;
        gb1 = xpb + ((size_t)b * XPAD_STRIDE + (size_t)tc * 512) * 2 + sc * 16;
    }

    // ---- ds_read bases: byte = row*64 + ((kq ^ (row>>1))&3)*16
    const unsigned swz = (unsigned)(((kq ^ (fr >> 1)) & 3) << 4);
    const unsigned offA_base = (unsigned)((wm * 64 + fr) * 64) + swz;
    const unsigned offB_base = (unsigned)((wn * 64 + fr) * 64) + swz;

    f32x4 acc[4][4];
    #pragma unroll
    for (int m = 0; m < 4; ++m)
        #pragma unroll
        for (int n = 0; n < 4; ++n)
            acc[m][n] = f32x4{0.f, 0.f, 0.f, 0.f};

    // ---- prologue: STG0 (3 out), STG1 (6 out); VM3 drains STG0; barrier
    STG(0, 0)
    STG(1, 1)
    VM3
    __builtin_amdgcn_s_barrier();
    __builtin_amdgcn_sched_barrier(0);

    // ---- main loop: phases 0..59 (slot period 3; 6-phase unroll keeps ph affine)
    #pragma unroll 1
    for (int i = 0; i < 10; ++i) {
        const int t = 6 * i;
        PH(0, STG(t + 2, 2), VM3)   // p=t+0
        PH(1, STG(t + 3, 0), VM3)   // p=t+1
        PH(2, STG(t + 4, 1), VM3)   // p=t+2
        PH(0, STG(t + 5, 2), VM3)   // p=t+3
        PH(1, STG(t + 6, 0), VM3)   // p=t+4
        PH(2, STG(t + 7, 1), VM3)   // p=t+5
    }
    // ---- tail: phases 60..63
    PH(0, STG(62, 2), VM3)          // p=60
    PH(1, STG(63, 0), VM3)          // p=61
    PH(2, , VM0)                    // p=62
    PH(0, , )                       // p=63 (slot 0 drained by p=62's VM0+barrier)

    // ---- epilogue: C/D layout col = lane&15, row = kq*4 + j
    const size_t imag_base = (size_t)B_BATCH * NFREQ * T_OUT;
    #pragma unroll
    for (int n = 0; n < 4; ++n) {
        const int col = nt * 256 + wn * 64 + n * 16 + fr;
        if (col < NCOLS) {
            const unsigned b = (unsigned)col / 626u;
            const int tc = col - (int)b * 626;
            const size_t colbase = (size_t)b * NFREQ * T_OUT + (size_t)tc;
            #pragma unroll
            for (int m = 0; m < 4; ++m) {
                #pragma unroll
                for (int j = 0; j < 4; ++j) {
                    const int grow = mt * 128 + wm * 64 + m * 16 + kq * 4 + j;
                    if (grow < M_ROWS) {
                        const size_t off = (grow < NFREQ)
                            ? colbase + (size_t)grow * T_OUT
                            : imag_base + colbase + (size_t)(grow - NFREQ) * T_OUT;
                        out[off] = acc[m][n][j];
                    }
                }
            }
        }
    }
}

// ---------------- no-workspace fallback (round-1 structure) ----------------
__device__ __forceinline__ unsigned lds_off_fb(int row, int kbyte) {
    return (unsigned)(row * 128 + (kbyte ^ ((row & 7) << 4)));
}

__global__ __launch_bounds__(256) void stft_gemm_fb(
    const float* __restrict__ x,
    const float* __restrict__ wre,
    const float* __restrict__ wim,
    float* __restrict__ out)
{
    __shared__ __align__(16) unsigned char ldsA[128 * 128];
    __shared__ __align__(16) unsigned char ldsB[128 * 128];

    const int tid  = threadIdx.x;
    const int lane = tid & 63;
    const int wid  = tid >> 6;
    const int wmf  = wid >> 1;
    const int wnf  = wid & 1;

    const int bid = blockIdx.x;
    const int b   = bid / (17 * 5);
    const int rem = bid % (17 * 5);
    const int mt  = rem / 5;
    const int nt  = rem % 5;

    const int row0 = mt * 128;
    const int col0 = nt * 128;
    const float* xb = x + (size_t)b * XLEN;

    const int c4 = (tid & 15) * 4;
    const int r0 = tid >> 4;

    f32x4 acc[4][4];
    #pragma unroll
    for (int m = 0; m < 4; ++m)
        #pragma unroll
        for (int n = 0; n < 4; ++n)
            acc[m][n] = f32x4{0.f, 0.f, 0.f, 0.f};

    const int fr = lane & 15;
    const int kq = lane >> 4;

    for (int k0 = 0; k0 < NFFT; k0 += 64) {
        bf16x4 sa[8], sb[8];
        #pragma unroll
        for (int rr = 0; rr < 8; ++rr) {
            const int row  = rr * 16 + r0;
            const int grow = row0 + row;
            float4 v = make_float4(0.f, 0.f, 0.f, 0.f);
            if (grow < M_ROWS) {
                const float* wsrc = (grow < NFREQ)
                    ? (wre + (size_t)grow * NFFT)
                    : (wim + (size_t)(grow - NFREQ) * NFFT);
                v = *reinterpret_cast<const float4*>(wsrc + k0 + c4);
            }
            sa[rr].x = (__bf16)v.x; sa[rr].y = (__bf16)v.y;
            sa[rr].z = (__bf16)v.z; sa[rr].w = (__bf16)v.w;
        }
        #pragma unroll
        for (int rr = 0; rr < 8; ++rr) {
            const int trow = rr * 16 + r0;
            const int t    = col0 + trow;
            float4 v = make_float4(0.f, 0.f, 0.f, 0.f);
            if (t < T_OUT) {
                const int pos = t * HOP + k0 + c4 - PADW;
                if (pos >= 0 && pos <= XLEN - 4) {
                    v = *reinterpret_cast<const float4*>(xb + pos);
                } else {
                    float tmp[4];
                    #pragma unroll
                    for (int e = 0; e < 4; ++e) {
                        int p = pos + e;
                        p = (p < 0) ? -p : p;
                        p = (p >= XLEN) ? (2 * XLEN - 2 - p) : p;
                        tmp[e] = xb[p];
                    }
                    v = make_float4(tmp[0], tmp[1], tmp[2], tmp[3]);
                }
            }
            sb[rr].x = (__bf16)v.x; sb[rr].y = (__bf16)v.y;
            sb[rr].z = (__bf16)v.z; sb[rr].w = (__bf16)v.w;
        }
        __syncthreads();
        #pragma unroll
        for (int rr = 0; rr < 8; ++rr) {
            const int row = rr * 16 + r0;
            *reinterpret_cast<bf16x4*>(ldsA + lds_off_fb(row, c4 * 2)) = sa[rr];
            *reinterpret_cast<bf16x4*>(ldsB + lds_off_fb(row, c4 * 2)) = sb[rr];
        }
        __syncthreads();
        #pragma unroll
        for (int kk = 0; kk < 2; ++kk) {
            const int kbyte = kk * 64 + kq * 16;
            bf16x8 af[4], bfv[4];
            #pragma unroll
            for (int m = 0; m < 4; ++m)
                af[m] = *reinterpret_cast<const bf16x8*>(
                    ldsA + lds_off_fb(wmf * 64 + m * 16 + fr, kbyte));
            #pragma unroll
            for (int n = 0; n < 4; ++n)
                bfv[n] = *reinterpret_cast<const bf16x8*>(
                    ldsB + lds_off_fb(wnf * 64 + n * 16 + fr, kbyte));
            #pragma unroll
            for (int m = 0; m < 4; ++m)
                #pragma unroll
                for (int n = 0; n < 4; ++n)
                    acc[m][n] = MFMA16(af[m], bfv[n], acc[m][n], 0, 0, 0);
        }
    }

    const size_t imag_base = (size_t)B_BATCH * NFREQ * T_OUT;
    #pragma unroll
    for (int m = 0; m < 4; ++m) {
        #pragma unroll
        for (int n = 0; n < 4; ++n) {
            #pragma unroll
            for (int j = 0; j < 4; ++j) {
                const int grow = row0 + wmf * 64 + m * 16 + kq * 4 + j;
                const int gcol = col0 + wnf * 64 + n * 16 + fr;
                if (grow < M_ROWS && gcol < T_OUT) {
                    size_t off;
                    if (grow < NFREQ)
                        off = ((size_t)b * NFREQ + grow) * T_OUT + gcol;
                    else
                        off = imag_base + ((size_t)b * NFREQ + (grow - NFREQ)) * T_OUT + gcol;
                    out[off] = acc[m][n][j];
                }
            }
        }
    }
}

extern "C" void kernel_launch(void* const* d_in, const int* in_sizes, int n_in,
                              void* d_out, int out_size, void* d_ws, size_t ws_size,
                              hipStream_t stream) {
    const float* x   = (const float*)d_in[0];
    const float* wre = (const float*)d_in[1];
    const float* wim = (const float*)d_in[2];
    float* out = (float*)d_out;

    if (ws_size < WS_NEEDED) {
        stft_gemm_fb<<<dim3(B_BATCH * 17 * 5), 256, 0, stream>>>(x, wre, wim, out);
        return;
    }

    __bf16* apack = (__bf16*)d_ws;
    __bf16* xpad  = (__bf16*)((char*)d_ws + APACK_BYTES);

    prep_w<<<dim3(557056 / 256), 256, 0, stream>>>(wre, wim, apack);
    prep_x<<<dim3(((B_BATCH + 1) * (XPAD_STRIDE / 8) + 255) / 256), 256, 0, stream>>>(x, xpad);
    stft_gemm7<<<dim3(NBLK), 512, 0, stream>>>(apack, xpad, out);
}